// Round 1
// baseline (1429.343 us; speedup 1.0000x reference)
//
#include <hip/hip_runtime.h>
#include <stdint.h>

typedef __attribute__((ext_vector_type(8))) short short8;
typedef __attribute__((ext_vector_type(4))) float f32x4;
typedef unsigned short u16;
typedef unsigned int u32;

#define NTOK 4096   // B*S
#define E 2048
#define S 2048
#define NH 16
#define NKVH 4
#define HD 128

__device__ __forceinline__ float bf2f(u16 u) {
    return __uint_as_float(((u32)u) << 16);
}
__device__ __forceinline__ u16 f2bf(float f) {
    u32 u = __float_as_uint(f);
    u32 r = (u + 0x7fffu + ((u >> 16) & 1u)) >> 16;
    return (u16)r;
}
__device__ __forceinline__ void unpack8(int4 v, float* o) {
    u32 a;
    a = (u32)v.x; o[0] = __uint_as_float(a << 16); o[1] = __uint_as_float(a & 0xffff0000u);
    a = (u32)v.y; o[2] = __uint_as_float(a << 16); o[3] = __uint_as_float(a & 0xffff0000u);
    a = (u32)v.z; o[4] = __uint_as_float(a << 16); o[5] = __uint_as_float(a & 0xffff0000u);
    a = (u32)v.w; o[6] = __uint_as_float(a << 16); o[7] = __uint_as_float(a & 0xffff0000u);
}

// ---------------- fp32 -> bf16 cast (flat) ----------------
__global__ void cvtbf(const float* __restrict__ src, u16* __restrict__ dst, int n4) {
    int i = blockIdx.x * 256 + threadIdx.x;
    if (i >= n4) return;
    float4 v = *(const float4*)(src + (size_t)i * 4);
    ushort4 o;
    o.x = f2bf(v.x); o.y = f2bf(v.y); o.z = f2bf(v.z); o.w = f2bf(v.w);
    *(ushort4*)(dst + (size_t)i * 4) = o;
}

// ---------------- bf16 GEMM, C[M,N] = A[M,K] * Bt[N,K]^T  (both K-contiguous) ----------------
#define TM 128
#define TN 128
#define BK 64
#define LDK 72   // padded LDS stride (bf16 elems); 144B = 9*16B keeps b128 alignment

__global__ __launch_bounds__(256, 2)
void gemm_bt(const u16* __restrict__ A, const u16* __restrict__ Bt, float* __restrict__ C,
             int M, int N, int K) {
    __shared__ u16 As[TM * LDK];
    __shared__ u16 Bs[TN * LDK];
    const int m0 = blockIdx.y * TM;
    const int n0 = blockIdx.x * TN;
    const int tid = threadIdx.x;
    const int w = tid >> 6, lane = tid & 63;
    const int wm = (w >> 1) * 64, wn = (w & 1) * 64;
    const int lr = lane & 15, quad = lane >> 4;

    f32x4 acc[4][4];
#pragma unroll
    for (int mi = 0; mi < 4; mi++)
#pragma unroll
        for (int ni = 0; ni < 4; ni++)
            acc[mi][ni] = (f32x4){0.f, 0.f, 0.f, 0.f};

    const int tr = tid >> 3;          // 0..31
    const int tc = (tid & 7) * 8;     // 0,8,..,56

    for (int kt = 0; kt < K; kt += BK) {
        __syncthreads();
#pragma unroll
        for (int i = 0; i < 4; i++) {
            int r = tr + 32 * i;
            int4 va = *(const int4*)(A + (size_t)(m0 + r) * K + kt + tc);
            *(int4*)(&As[r * LDK + tc]) = va;
            int4 vb = *(const int4*)(Bt + (size_t)(n0 + r) * K + kt + tc);
            *(int4*)(&Bs[r * LDK + tc]) = vb;
        }
        __syncthreads();
#pragma unroll
        for (int kk = 0; kk < BK; kk += 32) {
            const int ko = kk + quad * 8;
            short8 af[4], bfr[4];
#pragma unroll
            for (int mi = 0; mi < 4; mi++)
                af[mi] = *(const short8*)(&As[(wm + mi * 16 + lr) * LDK + ko]);
#pragma unroll
            for (int ni = 0; ni < 4; ni++)
                bfr[ni] = *(const short8*)(&Bs[(wn + ni * 16 + lr) * LDK + ko]);
#pragma unroll
            for (int mi = 0; mi < 4; mi++)
#pragma unroll
                for (int ni = 0; ni < 4; ni++)
                    acc[mi][ni] = __builtin_amdgcn_mfma_f32_16x16x32_bf16(
                        af[mi], bfr[ni], acc[mi][ni], 0, 0, 0);
        }
    }
    // epilogue: D row = quad*4+reg, col = lane&15  [measured m89/m91]
#pragma unroll
    for (int mi = 0; mi < 4; mi++)
#pragma unroll
        for (int ni = 0; ni < 4; ni++) {
            int row = m0 + wm + mi * 16 + quad * 4;
            int col = n0 + wn + ni * 16 + lr;
            f32x4 v = acc[mi][ni];
            C[(size_t)(row + 0) * N + col] = v[0];
            C[(size_t)(row + 1) * N + col] = v[1];
            C[(size_t)(row + 2) * N + col] = v[2];
            C[(size_t)(row + 3) * N + col] = v[3];
        }
}

// ---------------- RMSNorm + RoPE, relayout (n, h*D+d) -> (b,h,s,d), bf16 out ----------------
__global__ __launch_bounds__(256)
void rmsrope(const float* __restrict__ src, const float* __restrict__ w,
             u16* __restrict__ dst, int HH) {
    int p = blockIdx.x * 4 + (threadIdx.x >> 6);
    int lane = threadIdx.x & 63;
    int n = p / HH;
    int h = p - n * HH;
    int b = n >> 11;          // n / S
    int s = n & 2047;         // n % S
    const float* row = src + (size_t)n * (HH * HD) + h * HD;
    float t1 = row[lane];
    float t2 = row[lane + 64];
    float ss = t1 * t1 + t2 * t2;
#pragma unroll
    for (int o = 1; o < 64; o <<= 1) ss += __shfl_xor(ss, o);
    float r = rsqrtf(ss * (1.f / 128.f) + 1e-6f);
    float a1 = t1 * r * w[lane];
    float a2 = t2 * r * w[lane + 64];
    // inv_freq = exp(-lane * ln(10000)/64)
    float freq = expf(lane * -0.14391156831212787f);
    float ang = (float)s * freq;
    float sn, cs;
    sincosf(ang, &sn, &cs);
    float o1 = a1 * cs - a2 * sn;
    float o2 = a2 * cs + a1 * sn;
    size_t base = (((size_t)(b * HH + h)) * S + s) * HD;
    dst[base + lane] = f2bf(o1);
    dst[base + 64 + lane] = f2bf(o2);
}

// ---------------- V: cast + relayout (n, kh*D+d) -> (b,kh,s,d) ----------------
__global__ void vcast(const float* __restrict__ src, u16* __restrict__ dst) {
    int idx = blockIdx.x * 256 + threadIdx.x;   // one per 4 elems; 524288 total
    int g = idx * 4;
    int n = g >> 9;           // /512
    int c = g & 511;
    int kh = c >> 7, d = c & 127;
    int b = n >> 11, s = n & 2047;
    float4 v = *(const float4*)(src + (size_t)n * 512 + c);
    ushort4 o;
    o.x = f2bf(v.x); o.y = f2bf(v.y); o.z = f2bf(v.z); o.w = f2bf(v.w);
    size_t dsti = (((size_t)(b * NKVH + kh)) * S + s) * HD + d;
    *(ushort4*)(dst + dsti) = o;
}

// ---------------- flash attention (vector fp32, online softmax, window+causal+softcap) ----
// block: 64 queries x 1 head; 4 lanes/query each own d-slice {i*16+dp*4 .. +3}
__global__ __launch_bounds__(256)
void attn_kernel(const u16* __restrict__ qa, const u16* __restrict__ ka,
                 const u16* __restrict__ va, u16* __restrict__ out) {
    __shared__ float ks[64 * 128];
    __shared__ float vs[64 * 128];
    const int tid = threadIdx.x;
    const int qt = blockIdx.x, h = blockIdx.y, b = blockIdx.z;
    const int kh = h >> 2;
    const int q0 = qt * 64;
    const int qi = tid >> 2, dp = tid & 3;
    const int iq = q0 + qi;

    const float QSCALE = 0.0017677669529663689f;  // 1/(sqrt(128)*50)
    const u16* qrow = qa + (((size_t)(b * NH + h)) * S + iq) * HD;
    float4 qf[8], of[8];
#pragma unroll
    for (int i = 0; i < 8; i++) {
        int d = i * 16 + dp * 4;
        ushort4 u = *(const ushort4*)(qrow + d);
        qf[i].x = bf2f(u.x) * QSCALE;
        qf[i].y = bf2f(u.y) * QSCALE;
        qf[i].z = bf2f(u.z) * QSCALE;
        qf[i].w = bf2f(u.w) * QSCALE;
        of[i].x = 0.f; of[i].y = 0.f; of[i].z = 0.f; of[i].w = 0.f;
    }
    float m = -1e30f, l = 0.f;

    const size_t kvbase = (((size_t)(b * NKVH + kh)) * S) * HD;
    int jt0 = q0 - 960; if (jt0 < 0) jt0 = 0;
    for (int jt = jt0; jt <= q0; jt += 64) {
        __syncthreads();
        const int4* kp = (const int4*)(ka + kvbase + (size_t)jt * HD);
        const int4* vp = (const int4*)(va + kvbase + (size_t)jt * HD);
#pragma unroll
        for (int c = 0; c < 4; c++) {
            int g = c * 256 + tid;
            unpack8(kp[g], ks + g * 8);
            unpack8(vp[g], vs + g * 8);
        }
        __syncthreads();
#pragma unroll 1
        for (int j = 0; j < 64; j++) {
            int jg = jt + j;
            bool valid = (jg <= iq) && (iq - jg < 1024);
            const float* kr = ks + j * 128;
            float acc = 0.f;
#pragma unroll
            for (int i = 0; i < 8; i++) {
                float4 kv = *(const float4*)(kr + i * 16 + dp * 4);
                acc = fmaf(qf[i].x, kv.x, acc);
                acc = fmaf(qf[i].y, kv.y, acc);
                acc = fmaf(qf[i].z, kv.z, acc);
                acc = fmaf(qf[i].w, kv.w, acc);
            }
            acc += __shfl_xor(acc, 1);
            acc += __shfl_xor(acc, 2);
            float sc = 50.f * tanhf(acc);        // soft cap (score/sqrtD/50 folded into q)
            float mn = valid ? fmaxf(m, sc) : m;
            float alpha = __expf(m - mn);
            float p = valid ? __expf(sc - mn) : 0.f;
            l = l * alpha + p;
            const float* vr = vs + j * 128;
#pragma unroll
            for (int i = 0; i < 8; i++) {
                float4 vv = *(const float4*)(vr + i * 16 + dp * 4);
                of[i].x = fmaf(of[i].x, alpha, p * vv.x);
                of[i].y = fmaf(of[i].y, alpha, p * vv.y);
                of[i].z = fmaf(of[i].z, alpha, p * vv.z);
                of[i].w = fmaf(of[i].w, alpha, p * vv.w);
            }
            m = mn;
        }
    }
    float inv_l = 1.f / l;
    u16* orow = out + ((size_t)(b * S + iq)) * E + h * HD;
#pragma unroll
    for (int i = 0; i < 8; i++) {
        int d = i * 16 + dp * 4;
        ushort4 o;
        o.x = f2bf(of[i].x * inv_l);
        o.y = f2bf(of[i].y * inv_l);
        o.z = f2bf(of[i].z * inv_l);
        o.w = f2bf(of[i].w * inv_l);
        *(ushort4*)(orow + d) = o;
    }
}

// ---------------- residual + LayerNorm ----------------
__global__ __launch_bounds__(256)
void ln_kernel(const float* __restrict__ x, const float* __restrict__ pr,
               const float* __restrict__ g, const float* __restrict__ be,
               float* __restrict__ out) {
    int n = blockIdx.x;
    int tid = threadIdx.x;
    const float* xr = x + (size_t)n * E;
    const float* p = pr + (size_t)n * E;
    float y[8];
    float s = 0.f, ss = 0.f;
#pragma unroll
    for (int i = 0; i < 2; i++) {
        float4 a = *(const float4*)(xr + tid * 8 + i * 4);
        float4 b = *(const float4*)(p + tid * 8 + i * 4);
        float v0 = a.x + b.x, v1 = a.y + b.y, v2 = a.z + b.z, v3 = a.w + b.w;
        y[i * 4 + 0] = v0; y[i * 4 + 1] = v1; y[i * 4 + 2] = v2; y[i * 4 + 3] = v3;
        s += v0 + v1 + v2 + v3;
        ss += v0 * v0 + v1 * v1 + v2 * v2 + v3 * v3;
    }
#pragma unroll
    for (int o = 1; o < 64; o <<= 1) {
        s += __shfl_xor(s, o);
        ss += __shfl_xor(ss, o);
    }
    __shared__ float r0[4], r1[4];
    int w = tid >> 6;
    if ((tid & 63) == 0) { r0[w] = s; r1[w] = ss; }
    __syncthreads();
    s = r0[0] + r0[1] + r0[2] + r0[3];
    ss = r1[0] + r1[1] + r1[2] + r1[3];
    float mu = s * (1.f / 2048.f);
    float var = ss * (1.f / 2048.f) - mu * mu;
    float rs = rsqrtf(var + 1e-5f);
    float* orow = out + (size_t)n * E;
#pragma unroll
    for (int i = 0; i < 8; i++) {
        int c = tid * 8 + i;
        orow[c] = (y[i] - mu) * rs * g[c] + be[c];
    }
}

// ---------------- launch ----------------
extern "C" void kernel_launch(void* const* d_in, const int* in_sizes, int n_in,
                              void* d_out, int out_size, void* d_ws, size_t ws_size,
                              hipStream_t stream) {
    (void)in_sizes; (void)n_in; (void)out_size; (void)ws_size;
    const float* x   = (const float*)d_in[0];
    const float* Wq  = (const float*)d_in[1];
    const float* Wk  = (const float*)d_in[2];
    const float* Wv  = (const float*)d_in[3];
    const float* Wo  = (const float*)d_in[4];
    const float* qnw = (const float*)d_in[5];
    const float* knw = (const float*)d_in[6];
    const float* lng = (const float*)d_in[7];
    const float* lnb = (const float*)d_in[8];
    float* out = (float*)d_out;

    char* ws = (char*)d_ws;
    size_t off = 0;
    auto alloc = [&](size_t bytes) -> char* {
        char* pp = ws + off;
        off = (off + bytes + 255) & ~(size_t)255;
        return pp;
    };
    u16*  xb   = (u16*)alloc((size_t)NTOK * E * 2);     // later reused as attn_out
    u16*  Wqb  = (u16*)alloc((size_t)E * E * 2);
    u16*  Wkb  = (u16*)alloc((size_t)512 * E * 2);
    u16*  Wvb  = (u16*)alloc((size_t)512 * E * 2);
    u16*  Wob  = (u16*)alloc((size_t)E * E * 2);
    float* qraw = (float*)alloc((size_t)NTOK * E * 4);  // later reused as proj
    float* kraw = (float*)alloc((size_t)NTOK * 512 * 4);
    float* vraw = (float*)alloc((size_t)NTOK * 512 * 4);
    u16*  qaa  = (u16*)alloc((size_t)NTOK * E * 2);
    u16*  kaa  = (u16*)alloc((size_t)NTOK * 512 * 2);
    u16*  vaa  = (u16*)alloc((size_t)NTOK * 512 * 2);
    u16*  attn_o = xb;
    float* proj  = qraw;

    // casts
    cvtbf<<<dim3((NTOK * E / 4) / 256), 256, 0, stream>>>(x, xb, NTOK * E / 4);
    cvtbf<<<dim3((E * E / 4) / 256), 256, 0, stream>>>(Wq, Wqb, E * E / 4);
    cvtbf<<<dim3((512 * E / 4) / 256), 256, 0, stream>>>(Wk, Wkb, 512 * E / 4);
    cvtbf<<<dim3((512 * E / 4) / 256), 256, 0, stream>>>(Wv, Wvb, 512 * E / 4);
    cvtbf<<<dim3((E * E / 4) / 256), 256, 0, stream>>>(Wo, Wob, E * E / 4);

    // QKV projections
    gemm_bt<<<dim3(E / TN, NTOK / TM), 256, 0, stream>>>(xb, Wqb, qraw, NTOK, E, E);
    gemm_bt<<<dim3(512 / TN, NTOK / TM), 256, 0, stream>>>(xb, Wkb, kraw, NTOK, 512, E);
    gemm_bt<<<dim3(512 / TN, NTOK / TM), 256, 0, stream>>>(xb, Wvb, vraw, NTOK, 512, E);

    // norms + rope + relayout
    rmsrope<<<dim3(NTOK * NH / 4), 256, 0, stream>>>(qraw, qnw, qaa, NH);
    rmsrope<<<dim3(NTOK * NKVH / 4), 256, 0, stream>>>(kraw, knw, kaa, NKVH);
    vcast<<<dim3((NTOK * 512 / 4) / 256), 256, 0, stream>>>(vraw, vaa);

    // attention
    attn_kernel<<<dim3(S / 64, NH, 2), 256, 0, stream>>>(qaa, kaa, vaa, attn_o);

    // output projection
    gemm_bt<<<dim3(E / TN, NTOK / TM), 256, 0, stream>>>(attn_o, Wob, proj, NTOK, E, E);

    // residual + layernorm
    ln_kernel<<<dim3(NTOK), 256, 0, stream>>>(x, proj, lng, lnb, out);
}

// Round 2
// 490.561 us; speedup vs baseline: 2.9137x; 2.9137x over previous
//
#include <hip/hip_runtime.h>
#include <stdint.h>

typedef __attribute__((ext_vector_type(8))) short short8;
typedef __attribute__((ext_vector_type(4))) float f32x4;
typedef unsigned short u16;
typedef unsigned int u32;

#define NTOK 4096   // B*S
#define E 2048
#define S 2048
#define NH 16
#define NKVH 4
#define HD 128

__device__ __forceinline__ float bf2f(u16 u) {
    return __uint_as_float(((u32)u) << 16);
}
__device__ __forceinline__ u16 f2bf(float f) {
    u32 u = __float_as_uint(f);
    u32 r = (u + 0x7fffu + ((u >> 16) & 1u)) >> 16;
    return (u16)r;
}

// ---------------- fp32 -> bf16 cast (flat) ----------------
__global__ void cvtbf(const float* __restrict__ src, u16* __restrict__ dst, int n4) {
    int i = blockIdx.x * 256 + threadIdx.x;
    if (i >= n4) return;
    float4 v = *(const float4*)(src + (size_t)i * 4);
    ushort4 o;
    o.x = f2bf(v.x); o.y = f2bf(v.y); o.z = f2bf(v.z); o.w = f2bf(v.w);
    *(ushort4*)(dst + (size_t)i * 4) = o;
}

// ---------------- bf16 GEMM, C[M,N] = A[M,K] * Bt[N,K]^T  (both K-contiguous) ----------------
#define TM 128
#define TN 128
#define BK 64
#define LDK 72   // padded LDS stride (bf16 elems)

__global__ __launch_bounds__(256, 2)
void gemm_bt(const u16* __restrict__ A, const u16* __restrict__ Bt, float* __restrict__ C,
             int M, int N, int K) {
    __shared__ u16 As[TM * LDK];
    __shared__ u16 Bs[TN * LDK];
    const int m0 = blockIdx.y * TM;
    const int n0 = blockIdx.x * TN;
    const int tid = threadIdx.x;
    const int w = tid >> 6, lane = tid & 63;
    const int wm = (w >> 1) * 64, wn = (w & 1) * 64;
    const int lr = lane & 15, quad = lane >> 4;

    f32x4 acc[4][4];
#pragma unroll
    for (int mi = 0; mi < 4; mi++)
#pragma unroll
        for (int ni = 0; ni < 4; ni++)
            acc[mi][ni] = (f32x4){0.f, 0.f, 0.f, 0.f};

    const int tr = tid >> 3;          // 0..31
    const int tc = (tid & 7) * 8;     // 0,8,..,56

    for (int kt = 0; kt < K; kt += BK) {
        __syncthreads();
#pragma unroll
        for (int i = 0; i < 4; i++) {
            int r = tr + 32 * i;
            int4 va = *(const int4*)(A + (size_t)(m0 + r) * K + kt + tc);
            *(int4*)(&As[r * LDK + tc]) = va;
            int4 vb = *(const int4*)(Bt + (size_t)(n0 + r) * K + kt + tc);
            *(int4*)(&Bs[r * LDK + tc]) = vb;
        }
        __syncthreads();
#pragma unroll
        for (int kk = 0; kk < BK; kk += 32) {
            const int ko = kk + quad * 8;
            short8 af[4], bfr[4];
#pragma unroll
            for (int mi = 0; mi < 4; mi++)
                af[mi] = *(const short8*)(&As[(wm + mi * 16 + lr) * LDK + ko]);
#pragma unroll
            for (int ni = 0; ni < 4; ni++)
                bfr[ni] = *(const short8*)(&Bs[(wn + ni * 16 + lr) * LDK + ko]);
#pragma unroll
            for (int mi = 0; mi < 4; mi++)
#pragma unroll
                for (int ni = 0; ni < 4; ni++)
                    acc[mi][ni] = __builtin_amdgcn_mfma_f32_16x16x32_bf16(
                        af[mi], bfr[ni], acc[mi][ni], 0, 0, 0);
        }
    }
#pragma unroll
    for (int mi = 0; mi < 4; mi++)
#pragma unroll
        for (int ni = 0; ni < 4; ni++) {
            int row = m0 + wm + mi * 16 + quad * 4;
            int col = n0 + wn + ni * 16 + lr;
            f32x4 v = acc[mi][ni];
            C[(size_t)(row + 0) * N + col] = v[0];
            C[(size_t)(row + 1) * N + col] = v[1];
            C[(size_t)(row + 2) * N + col] = v[2];
            C[(size_t)(row + 3) * N + col] = v[3];
        }
}

// ---------------- RMSNorm + RoPE, relayout (n, h*D+d) -> (b,h,s,d), bf16 out ----------------
__global__ __launch_bounds__(256)
void rmsrope(const float* __restrict__ src, const float* __restrict__ w,
             u16* __restrict__ dst, int HH) {
    int p = blockIdx.x * 4 + (threadIdx.x >> 6);
    int lane = threadIdx.x & 63;
    int n = p / HH;
    int h = p - n * HH;
    int b = n >> 11;
    int s = n & 2047;
    const float* row = src + (size_t)n * (HH * HD) + h * HD;
    float t1 = row[lane];
    float t2 = row[lane + 64];
    float ss = t1 * t1 + t2 * t2;
#pragma unroll
    for (int o = 1; o < 64; o <<= 1) ss += __shfl_xor(ss, o);
    float r = rsqrtf(ss * (1.f / 128.f) + 1e-6f);
    float a1 = t1 * r * w[lane];
    float a2 = t2 * r * w[lane + 64];
    float freq = expf(lane * -0.14391156831212787f);
    float ang = (float)s * freq;
    float sn, cs;
    sincosf(ang, &sn, &cs);
    float o1 = a1 * cs - a2 * sn;
    float o2 = a2 * cs + a1 * sn;
    size_t base = (((size_t)(b * HH + h)) * S + s) * HD;
    dst[base + lane] = f2bf(o1);
    dst[base + 64 + lane] = f2bf(o2);
}

// ---------------- V: cast + transpose (n, kh*D+d) fp32 -> Vt (b,kh,d,s) bf16 ----------------
#define LDT 65
__global__ __launch_bounds__(256)
void vtrans(const float* __restrict__ src, u16* __restrict__ dst) {
    __shared__ u16 Ts[128 * LDT];
    const int t = threadIdx.x;
    const int s0 = blockIdx.x * 64;
    const int kh = blockIdx.y;
    const int b = blockIdx.z;
    const float* base = src + ((size_t)(b * S + s0)) * 512 + kh * HD;
#pragma unroll
    for (int i = 0; i < 8; i++) {
        int idx = i * 256 + t;
        int r = idx >> 5, c4 = (idx & 31) * 4;
        float4 v = *(const float4*)(base + (size_t)r * 512 + c4);
        Ts[(c4 + 0) * LDT + r] = f2bf(v.x);
        Ts[(c4 + 1) * LDT + r] = f2bf(v.y);
        Ts[(c4 + 2) * LDT + r] = f2bf(v.z);
        Ts[(c4 + 3) * LDT + r] = f2bf(v.w);
    }
    __syncthreads();
    u16* obase = dst + ((size_t)(b * NKVH + kh) * HD) * S + s0;
#pragma unroll
    for (int i = 0; i < 4; i++) {
        int idx = i * 256 + t;
        int d = idx >> 3, s8 = (idx & 7) * 8;
        const u16* row = &Ts[d * LDT + s8];
        short8 o;
#pragma unroll
        for (int j = 0; j < 8; j++) o[j] = (short)row[j];
        *(short8*)(obase + (size_t)d * S + s8) = o;
    }
}

// ---------------- MFMA flash attention ----------------
// block: 64 queries x 1 head, 4 waves x 16 queries; KV tiles of 64 keys
#define LDKK 136   // Ks stride (128 d + pad), 272B rows (16B mult)
#define LDVS 72    // Vs stride (64 keys + pad)
#define LDP  72    // Ps stride

__global__ __launch_bounds__(256, 4)
void attn_mfma(const u16* __restrict__ qa, const u16* __restrict__ ka,
               const u16* __restrict__ vt, u16* __restrict__ out) {
    __shared__ u16 Ks[64 * LDKK];
    __shared__ u16 Vs[128 * LDVS];
    __shared__ u16 Ps[64 * LDP];
    const int tid = threadIdx.x;
    const int w = tid >> 6, lane = tid & 63;
    const int lr = lane & 15, quad = lane >> 4;
    const int qt = blockIdx.x, h = blockIdx.y, b = blockIdx.z;
    const int kh = h >> 2;
    const int q0 = qt * 64;
    const int qw0 = q0 + w * 16;

    const float SCINV = 0.0017677669529663689f;  // 1/(sqrt(128)*50)

    // Q fragments: [q=lane&15][d = c*32 + quad*8 + j]
    const u16* qrow = qa + (((size_t)(b * NH + h)) * S + qw0 + lr) * HD;
    short8 qf[4];
#pragma unroll
    for (int c = 0; c < 4; c++)
        qf[c] = *(const short8*)(qrow + c * 32 + quad * 8);

    f32x4 O[8];
#pragma unroll
    for (int dt = 0; dt < 8; dt++) O[dt] = (f32x4){0.f, 0.f, 0.f, 0.f};
    float m[4], l[4];
#pragma unroll
    for (int r = 0; r < 4; r++) { m[r] = -1e30f; l[r] = 0.f; }

    const u16* kbase0 = ka + (((size_t)(b * NKVH + kh)) * S) * HD;
    const u16* vtbase0 = vt + ((size_t)(b * NKVH + kh) * HD) * S;

    int jt0 = q0 - 960; if (jt0 < 0) jt0 = 0;
    for (int jt = jt0; jt <= q0; jt += 64) {
        __syncthreads();
        const u16* kbase = kbase0 + (size_t)jt * HD;
        const u16* vtbase = vtbase0 + jt;
#pragma unroll
        for (int i = 0; i < 4; i++) {
            int idx = i * 256 + tid;
            int key = idx >> 4, c8 = (idx & 15) * 8;
            *(int4*)(&Ks[key * LDKK + c8]) = *(const int4*)(kbase + (size_t)key * HD + c8);
            int dd = idx >> 3, s8 = (idx & 7) * 8;
            *(int4*)(&Vs[dd * LDVS + s8]) = *(const int4*)(vtbase + (size_t)dd * S + s8);
        }
        __syncthreads();

        // QK^T: scores [q=quad*4+r][key = kt*16 + lr]
        f32x4 sc[4];
#pragma unroll
        for (int kt = 0; kt < 4; kt++) {
            f32x4 a = (f32x4){0.f, 0.f, 0.f, 0.f};
#pragma unroll
            for (int c = 0; c < 4; c++) {
                short8 kf = *(const short8*)(&Ks[(kt * 16 + lr) * LDKK + c * 32 + quad * 8]);
                a = __builtin_amdgcn_mfma_f32_16x16x32_bf16(qf[c], kf, a, 0, 0, 0);
            }
            sc[kt] = a;
        }

        // softcap + mask + online softmax
#pragma unroll
        for (int r = 0; r < 4; r++) {
            int iq = qw0 + quad * 4 + r;
            float mx = -1e30f;
#pragma unroll
            for (int kt = 0; kt < 4; kt++) {
                float x = sc[kt][r] * SCINV;
                x = fminf(fmaxf(x, -15.f), 15.f);
                float t = __expf(2.f * x);
                float s2 = 50.f - 100.f / (t + 1.f);
                int jg = jt + kt * 16 + lr;
                bool valid = (jg <= iq) && (iq - jg < 1024);
                s2 = valid ? s2 : -1e30f;
                sc[kt][r] = s2;
                mx = fmaxf(mx, s2);
            }
            mx = fmaxf(mx, __shfl_xor(mx, 1));
            mx = fmaxf(mx, __shfl_xor(mx, 2));
            mx = fmaxf(mx, __shfl_xor(mx, 4));
            mx = fmaxf(mx, __shfl_xor(mx, 8));
            float mn = fmaxf(m[r], mx);
            float alpha = __expf(m[r] - mn);
            m[r] = mn;
            float rs = 0.f;
#pragma unroll
            for (int kt = 0; kt < 4; kt++) {
                float p = __expf(sc[kt][r] - mn);
                sc[kt][r] = p;
                rs += p;
            }
            rs += __shfl_xor(rs, 1);
            rs += __shfl_xor(rs, 2);
            rs += __shfl_xor(rs, 4);
            rs += __shfl_xor(rs, 8);
            l[r] = l[r] * alpha + rs;
#pragma unroll
            for (int dt = 0; dt < 8; dt++) O[dt][r] *= alpha;
        }

        // P (C-layout) -> LDS -> A-layout
        u16* Pw = &Ps[w * 16 * LDP];
#pragma unroll
        for (int r = 0; r < 4; r++)
#pragma unroll
            for (int kt = 0; kt < 4; kt++)
                Pw[(quad * 4 + r) * LDP + kt * 16 + lr] = f2bf(sc[kt][r]);

        // PV: O[q][d] += P[q][key] * Vt[d][key]
#pragma unroll
        for (int c2 = 0; c2 < 2; c2++) {
            short8 pf = *(const short8*)(&Pw[lr * LDP + c2 * 32 + quad * 8]);
#pragma unroll
            for (int dt = 0; dt < 8; dt++) {
                short8 vf = *(const short8*)(&Vs[(dt * 16 + lr) * LDVS + c2 * 32 + quad * 8]);
                O[dt] = __builtin_amdgcn_mfma_f32_16x16x32_bf16(pf, vf, O[dt], 0, 0, 0);
            }
        }
    }

    // epilogue: O[dt][r] for q = qw0+quad*4+r, d = dt*16+lr
#pragma unroll
    for (int r = 0; r < 4; r++) {
        float inv = 1.f / l[r];
        u16* orow = out + ((size_t)(b * S + qw0 + quad * 4 + r)) * E + h * HD;
#pragma unroll
        for (int dt = 0; dt < 8; dt++)
            orow[dt * 16 + lr] = f2bf(O[dt][r] * inv);
    }
}

// ---------------- residual + LayerNorm ----------------
__global__ __launch_bounds__(256)
void ln_kernel(const float* __restrict__ x, const float* __restrict__ pr,
               const float* __restrict__ g, const float* __restrict__ be,
               float* __restrict__ out) {
    int n = blockIdx.x;
    int tid = threadIdx.x;
    const float* xr = x + (size_t)n * E;
    const float* p = pr + (size_t)n * E;
    float y[8];
    float s = 0.f, ss = 0.f;
#pragma unroll
    for (int i = 0; i < 2; i++) {
        float4 a = *(const float4*)(xr + tid * 8 + i * 4);
        float4 b = *(const float4*)(p + tid * 8 + i * 4);
        float v0 = a.x + b.x, v1 = a.y + b.y, v2 = a.z + b.z, v3 = a.w + b.w;
        y[i * 4 + 0] = v0; y[i * 4 + 1] = v1; y[i * 4 + 2] = v2; y[i * 4 + 3] = v3;
        s += v0 + v1 + v2 + v3;
        ss += v0 * v0 + v1 * v1 + v2 * v2 + v3 * v3;
    }
#pragma unroll
    for (int o = 1; o < 64; o <<= 1) {
        s += __shfl_xor(s, o);
        ss += __shfl_xor(ss, o);
    }
    __shared__ float r0[4], r1[4];
    int w = tid >> 6;
    if ((tid & 63) == 0) { r0[w] = s; r1[w] = ss; }
    __syncthreads();
    s = r0[0] + r0[1] + r0[2] + r0[3];
    ss = r1[0] + r1[1] + r1[2] + r1[3];
    float mu = s * (1.f / 2048.f);
    float var = ss * (1.f / 2048.f) - mu * mu;
    float rs = rsqrtf(var + 1e-5f);
    float* orow = out + (size_t)n * E;
#pragma unroll
    for (int i = 0; i < 8; i++) {
        int c = tid * 8 + i;
        orow[c] = (y[i] - mu) * rs * g[c] + be[c];
    }
}

// ---------------- launch ----------------
extern "C" void kernel_launch(void* const* d_in, const int* in_sizes, int n_in,
                              void* d_out, int out_size, void* d_ws, size_t ws_size,
                              hipStream_t stream) {
    (void)in_sizes; (void)n_in; (void)out_size; (void)ws_size;
    const float* x   = (const float*)d_in[0];
    const float* Wq  = (const float*)d_in[1];
    const float* Wk  = (const float*)d_in[2];
    const float* Wv  = (const float*)d_in[3];
    const float* Wo  = (const float*)d_in[4];
    const float* qnw = (const float*)d_in[5];
    const float* knw = (const float*)d_in[6];
    const float* lng = (const float*)d_in[7];
    const float* lnb = (const float*)d_in[8];
    float* out = (float*)d_out;

    char* ws = (char*)d_ws;
    size_t off = 0;
    auto alloc = [&](size_t bytes) -> char* {
        char* pp = ws + off;
        off = (off + bytes + 255) & ~(size_t)255;
        return pp;
    };
    u16*  xb   = (u16*)alloc((size_t)NTOK * E * 2);     // later reused as attn_out
    u16*  Wqb  = (u16*)alloc((size_t)E * E * 2);
    u16*  Wkb  = (u16*)alloc((size_t)512 * E * 2);
    u16*  Wvb  = (u16*)alloc((size_t)512 * E * 2);
    u16*  Wob  = (u16*)alloc((size_t)E * E * 2);
    float* qraw = (float*)alloc((size_t)NTOK * E * 4);  // later reused as proj
    float* kraw = (float*)alloc((size_t)NTOK * 512 * 4);
    float* vraw = (float*)alloc((size_t)NTOK * 512 * 4);
    u16*  qaa  = (u16*)alloc((size_t)NTOK * E * 2);
    u16*  kaa  = (u16*)alloc((size_t)NTOK * 512 * 2);
    u16*  vtt  = (u16*)alloc((size_t)NTOK * 512 * 2);
    u16*  attn_o = xb;
    float* proj  = qraw;

    cvtbf<<<dim3((NTOK * E / 4) / 256), 256, 0, stream>>>(x, xb, NTOK * E / 4);
    cvtbf<<<dim3((E * E / 4) / 256), 256, 0, stream>>>(Wq, Wqb, E * E / 4);
    cvtbf<<<dim3((512 * E / 4) / 256), 256, 0, stream>>>(Wk, Wkb, 512 * E / 4);
    cvtbf<<<dim3((512 * E / 4) / 256), 256, 0, stream>>>(Wv, Wvb, 512 * E / 4);
    cvtbf<<<dim3((E * E / 4) / 256), 256, 0, stream>>>(Wo, Wob, E * E / 4);

    gemm_bt<<<dim3(E / TN, NTOK / TM), 256, 0, stream>>>(xb, Wqb, qraw, NTOK, E, E);
    gemm_bt<<<dim3(512 / TN, NTOK / TM), 256, 0, stream>>>(xb, Wkb, kraw, NTOK, 512, E);
    gemm_bt<<<dim3(512 / TN, NTOK / TM), 256, 0, stream>>>(xb, Wvb, vraw, NTOK, 512, E);

    rmsrope<<<dim3(NTOK * NH / 4), 256, 0, stream>>>(qraw, qnw, qaa, NH);
    rmsrope<<<dim3(NTOK * NKVH / 4), 256, 0, stream>>>(kraw, knw, kaa, NKVH);
    vtrans<<<dim3(S / 64, NKVH, 2), 256, 0, stream>>>(vraw, vtt);

    attn_mfma<<<dim3(S / 64, NH, 2), 256, 0, stream>>>(qaa, kaa, vtt, attn_o);

    gemm_bt<<<dim3(E / TN, NTOK / TM), 256, 0, stream>>>(attn_o, Wob, proj, NTOK, E, E);

    ln_kernel<<<dim3(NTOK), 256, 0, stream>>>(x, proj, lng, lnb, out);
}

// Round 3
// 395.046 us; speedup vs baseline: 3.6182x; 1.2418x over previous
//
#include <hip/hip_runtime.h>
#include <stdint.h>

typedef __attribute__((ext_vector_type(8))) short short8;
typedef __attribute__((ext_vector_type(4))) float f32x4;
typedef unsigned short u16;
typedef unsigned int u32;

#define NTOK 4096   // B*S
#define E 2048
#define S 2048
#define NH 16
#define NKVH 4
#define HD 128

__device__ __forceinline__ float bf2f(u16 u) {
    return __uint_as_float(((u32)u) << 16);
}
__device__ __forceinline__ u16 f2bf(float f) {
    u32 u = __float_as_uint(f);
    u32 r = (u + 0x7fffu + ((u >> 16) & 1u)) >> 16;
    return (u16)r;
}
__device__ __forceinline__ void gload_lds16(const u16* g, u16* l) {
    __builtin_amdgcn_global_load_lds(
        (const __attribute__((address_space(1))) unsigned int*)(g),
        (__attribute__((address_space(3))) unsigned int*)(l), 16, 0, 0);
}

// ---------------- fp32 -> bf16 cast (flat) ----------------
__global__ void cvtbf(const float* __restrict__ src, u16* __restrict__ dst, int n4) {
    int i = blockIdx.x * 256 + threadIdx.x;
    if (i >= n4) return;
    float4 v = *(const float4*)(src + (size_t)i * 4);
    ushort4 o;
    o.x = f2bf(v.x); o.y = f2bf(v.y); o.z = f2bf(v.z); o.w = f2bf(v.w);
    *(ushort4*)(dst + (size_t)i * 4) = o;
}

// ---------------- bf16 GEMM, C[M,N] = A[M,K] * Bt[N,K]^T, m97-style async staging ----------
#define TM 128
#define TN 128
#define BK 64

__global__ __launch_bounds__(256, 2)
void gemm_bt(const u16* __restrict__ A, const u16* __restrict__ Bt, float* __restrict__ C,
             int M, int N, int K) {
    __shared__ u16 As[TM * BK];
    __shared__ u16 Bs[TN * BK];
    const int m0 = blockIdx.y * TM;
    const int n0 = blockIdx.x * TN;
    const int tid = threadIdx.x;
    const int w = tid >> 6, lane = tid & 63;
    const int wm = (w >> 1) * 64, wn = (w & 1) * 64;
    const int lr = lane & 15, quad = lane >> 4;

    f32x4 acc[4][4];
#pragma unroll
    for (int mi = 0; mi < 4; mi++)
#pragma unroll
        for (int ni = 0; ni < 4; ni++)
            acc[mi][ni] = (f32x4){0.f, 0.f, 0.f, 0.f};

    // staging: wave w stages rows [w*8 + i*32, +8); lane L -> row L>>3, col (L&7)*8
    const int srow = w * 8 + (lane >> 3);
    const int scol = (lane & 7) * 8;
    const u16* ga0 = A + (size_t)(m0 + srow) * K + scol;
    const u16* gb0 = Bt + (size_t)(n0 + srow) * K + scol;

    for (int kt = 0; kt < K; kt += BK) {
        __syncthreads();
#pragma unroll
        for (int i = 0; i < 4; i++) {
            gload_lds16(ga0 + (size_t)(i * 32) * K + kt, &As[(w * 8 + i * 32) * BK]);
            gload_lds16(gb0 + (size_t)(i * 32) * K + kt, &Bs[(w * 8 + i * 32) * BK]);
        }
        __syncthreads();
#pragma unroll
        for (int kk = 0; kk < BK; kk += 32) {
            const int ko = kk + quad * 8;
            short8 af[4], bfr[4];
#pragma unroll
            for (int mi = 0; mi < 4; mi++)
                af[mi] = *(const short8*)(&As[(wm + mi * 16 + lr) * BK + ko]);
#pragma unroll
            for (int ni = 0; ni < 4; ni++)
                bfr[ni] = *(const short8*)(&Bs[(wn + ni * 16 + lr) * BK + ko]);
#pragma unroll
            for (int mi = 0; mi < 4; mi++)
#pragma unroll
                for (int ni = 0; ni < 4; ni++)
                    acc[mi][ni] = __builtin_amdgcn_mfma_f32_16x16x32_bf16(
                        af[mi], bfr[ni], acc[mi][ni], 0, 0, 0);
        }
    }
#pragma unroll
    for (int mi = 0; mi < 4; mi++)
#pragma unroll
        for (int ni = 0; ni < 4; ni++) {
            int row = m0 + wm + mi * 16 + quad * 4;
            int col = n0 + wn + ni * 16 + lr;
            f32x4 v = acc[mi][ni];
            C[(size_t)(row + 0) * N + col] = v[0];
            C[(size_t)(row + 1) * N + col] = v[1];
            C[(size_t)(row + 2) * N + col] = v[2];
            C[(size_t)(row + 3) * N + col] = v[3];
        }
}

// ---------------- RMSNorm + RoPE, relayout (n, h*D+d) -> (b,h,s,d), bf16 out ----------------
__global__ __launch_bounds__(256)
void rmsrope(const float* __restrict__ src, const float* __restrict__ w,
             u16* __restrict__ dst, int HH, int rowstride) {
    int p = blockIdx.x * 4 + (threadIdx.x >> 6);
    int lane = threadIdx.x & 63;
    int n = p / HH;
    int h = p - n * HH;
    int b = n >> 11;
    int s = n & 2047;
    const float* row = src + (size_t)n * rowstride + h * HD;
    float t1 = row[lane];
    float t2 = row[lane + 64];
    float ss = t1 * t1 + t2 * t2;
#pragma unroll
    for (int o = 1; o < 64; o <<= 1) ss += __shfl_xor(ss, o);
    float r = rsqrtf(ss * (1.f / 128.f) + 1e-6f);
    float a1 = t1 * r * w[lane];
    float a2 = t2 * r * w[lane + 64];
    float freq = expf(lane * -0.14391156831212787f);
    float ang = (float)s * freq;
    float sn, cs;
    sincosf(ang, &sn, &cs);
    float o1 = a1 * cs - a2 * sn;
    float o2 = a2 * cs + a1 * sn;
    size_t base = (((size_t)(b * HH + h)) * S + s) * HD;
    dst[base + lane] = f2bf(o1);
    dst[base + 64 + lane] = f2bf(o2);
}

// ---------------- V: cast + transpose (n, 512 + kh*D+d of kv) fp32 -> Vt (b,kh,d,s) bf16 ----
#define LDT 65
__global__ __launch_bounds__(256)
void vtrans(const float* __restrict__ src, u16* __restrict__ dst) {
    __shared__ u16 Ts[128 * LDT];
    const int t = threadIdx.x;
    const int s0 = blockIdx.x * 64;
    const int kh = blockIdx.y;
    const int b = blockIdx.z;
    const float* base = src + ((size_t)(b * S + s0)) * 1024 + 512 + kh * HD;
#pragma unroll
    for (int i = 0; i < 8; i++) {
        int idx = i * 256 + t;
        int r = idx >> 5, c4 = (idx & 31) * 4;
        float4 v = *(const float4*)(base + (size_t)r * 1024 + c4);
        Ts[(c4 + 0) * LDT + r] = f2bf(v.x);
        Ts[(c4 + 1) * LDT + r] = f2bf(v.y);
        Ts[(c4 + 2) * LDT + r] = f2bf(v.z);
        Ts[(c4 + 3) * LDT + r] = f2bf(v.w);
    }
    __syncthreads();
    u16* obase = dst + ((size_t)(b * NKVH + kh) * HD) * S + s0;
#pragma unroll
    for (int i = 0; i < 4; i++) {
        int idx = i * 256 + t;
        int d = idx >> 3, s8 = (idx & 7) * 8;
        const u16* row = &Ts[d * LDT + s8];
        short8 o;
#pragma unroll
        for (int j = 0; j < 8; j++) o[j] = (short)row[j];
        *(short8*)(obase + (size_t)d * S + s8) = o;
    }
}

// ---------------- MFMA flash attention, fixed-max softmax (m=50) ----------------
// block: 64 queries x 1 head, 4 waves x 16 queries; KV tiles of 64 keys
#define LDKK 136   // Ks stride (128 d + pad)
#define LDVS 72    // Vs stride (64 keys + pad)
#define LDP  72    // Ps stride

__global__ __launch_bounds__(256, 3)
void attn_mfma(const u16* __restrict__ qa, const u16* __restrict__ ka,
               const u16* __restrict__ vt, u16* __restrict__ out) {
    __shared__ u16 Ks[64 * LDKK];
    __shared__ u16 Vs[128 * LDVS];
    __shared__ u16 Ps[64 * LDP];
    const int tid = threadIdx.x;
    const int w = tid >> 6, lane = tid & 63;
    const int lr = lane & 15, quad = lane >> 4;
    const int qt = blockIdx.x, h = blockIdx.y, b = blockIdx.z;
    const int kh = h >> 2;
    const int q0 = qt * 64;
    const int qw0 = q0 + w * 16;

    const float SCINV = 0.0017677669529663689f;  // 1/(sqrt(128)*50)

    // Q fragments: [q=lane&15][d = c*32 + quad*8 + j]
    const u16* qrow = qa + (((size_t)(b * NH + h)) * S + qw0 + lr) * HD;
    short8 qf[4];
#pragma unroll
    for (int c = 0; c < 4; c++)
        qf[c] = *(const short8*)(qrow + c * 32 + quad * 8);

    f32x4 O[8];
#pragma unroll
    for (int dt = 0; dt < 8; dt++) O[dt] = (f32x4){0.f, 0.f, 0.f, 0.f};
    float l[4] = {0.f, 0.f, 0.f, 0.f};

    const u16* kbase0 = ka + (((size_t)(b * NKVH + kh)) * S) * HD;
    const u16* vtbase0 = vt + ((size_t)(b * NKVH + kh) * HD) * S;

    const int jt0 = (q0 >= 1024) ? (q0 - 1024) : 0;
    for (int jt = jt0; jt <= q0; jt += 64) {
        __syncthreads();
        const u16* kbase = kbase0 + (size_t)jt * HD;
        const u16* vtbase = vtbase0 + jt;
#pragma unroll
        for (int i = 0; i < 4; i++) {
            int idx = i * 256 + tid;
            int key = idx >> 4, c8 = (idx & 15) * 8;
            *(int4*)(&Ks[key * LDKK + c8]) = *(const int4*)(kbase + (size_t)key * HD + c8);
            int dd = idx >> 3, s8 = (idx & 7) * 8;
            *(int4*)(&Vs[dd * LDVS + s8]) = *(const int4*)(vtbase + (size_t)dd * S + s8);
        }
        __syncthreads();

        const bool isDiag = (jt == q0);
        const bool isFirst = (q0 >= 1024) && (jt == jt0);
        u16* Pw = &Ps[w * 16 * LDP];

#pragma unroll
        for (int kt = 0; kt < 4; kt++) {
            // wave-uniform skip: fully-masked kt groups
            if ((isDiag && kt > w) || (isFirst && kt < w)) {
#pragma unroll
                for (int r = 0; r < 4; r++)
                    Pw[(quad * 4 + r) * LDP + kt * 16 + lr] = 0;
                continue;
            }
            f32x4 a = (f32x4){0.f, 0.f, 0.f, 0.f};
#pragma unroll
            for (int c = 0; c < 4; c++) {
                short8 kf = *(const short8*)(&Ks[(kt * 16 + lr) * LDKK + c * 32 + quad * 8]);
                a = __builtin_amdgcn_mfma_f32_16x16x32_bf16(qf[c], kf, a, 0, 0, 0);
            }
            const bool edge = (isDiag || isFirst) && (kt == w);
#pragma unroll
            for (int r = 0; r < 4; r++) {
                // p = exp(sc - 50), sc = 50*tanh(x) => p = exp(-100/(e^{2x}+1))
                float x = a[r] * SCINV;
                float t = __expf(2.f * x);
                float p = __expf(-100.f * __builtin_amdgcn_rcpf(t + 1.f));
                if (edge) {
                    int rel = kt * 16 + lr - (16 * w + quad * 4 + r);
                    bool valid = isDiag ? (rel <= 0) : (rel > 0);
                    p = valid ? p : 0.f;
                }
                l[r] += p;
                Pw[(quad * 4 + r) * LDP + kt * 16 + lr] = f2bf(p);
            }
        }

        // PV: O[q][d] += P[q][key] * Vt[d][key]
#pragma unroll
        for (int c2 = 0; c2 < 2; c2++) {
            if ((isDiag && 2 * c2 > w) || (isFirst && 2 * c2 + 1 < w)) continue;
            short8 pf = *(const short8*)(&Pw[lr * LDP + c2 * 32 + quad * 8]);
#pragma unroll
            for (int dt = 0; dt < 8; dt++) {
                short8 vf = *(const short8*)(&Vs[(dt * 16 + lr) * LDVS + c2 * 32 + quad * 8]);
                O[dt] = __builtin_amdgcn_mfma_f32_16x16x32_bf16(pf, vf, O[dt], 0, 0, 0);
            }
        }
    }

    // row-sum reduce across the 16 key-lanes (once, post-loop)
#pragma unroll
    for (int r = 0; r < 4; r++) {
        l[r] += __shfl_xor(l[r], 1);
        l[r] += __shfl_xor(l[r], 2);
        l[r] += __shfl_xor(l[r], 4);
        l[r] += __shfl_xor(l[r], 8);
    }
#pragma unroll
    for (int r = 0; r < 4; r++) {
        float inv = 1.f / l[r];
        u16* orow = out + ((size_t)(b * S + qw0 + quad * 4 + r)) * E + h * HD;
#pragma unroll
        for (int dt = 0; dt < 8; dt++)
            orow[dt * 16 + lr] = f2bf(O[dt][r] * inv);
    }
}

// ---------------- residual + LayerNorm ----------------
__global__ __launch_bounds__(256)
void ln_kernel(const float* __restrict__ x, const float* __restrict__ pr,
               const float* __restrict__ g, const float* __restrict__ be,
               float* __restrict__ out) {
    int n = blockIdx.x;
    int tid = threadIdx.x;
    const float* xr = x + (size_t)n * E;
    const float* p = pr + (size_t)n * E;
    float y[8];
    float s = 0.f, ss = 0.f;
#pragma unroll
    for (int i = 0; i < 2; i++) {
        float4 a = *(const float4*)(xr + tid * 8 + i * 4);
        float4 b = *(const float4*)(p + tid * 8 + i * 4);
        float v0 = a.x + b.x, v1 = a.y + b.y, v2 = a.z + b.z, v3 = a.w + b.w;
        y[i * 4 + 0] = v0; y[i * 4 + 1] = v1; y[i * 4 + 2] = v2; y[i * 4 + 3] = v3;
        s += v0 + v1 + v2 + v3;
        ss += v0 * v0 + v1 * v1 + v2 * v2 + v3 * v3;
    }
#pragma unroll
    for (int o = 1; o < 64; o <<= 1) {
        s += __shfl_xor(s, o);
        ss += __shfl_xor(ss, o);
    }
    __shared__ float r0[4], r1[4];
    int w = tid >> 6;
    if ((tid & 63) == 0) { r0[w] = s; r1[w] = ss; }
    __syncthreads();
    s = r0[0] + r0[1] + r0[2] + r0[3];
    ss = r1[0] + r1[1] + r1[2] + r1[3];
    float mu = s * (1.f / 2048.f);
    float var = ss * (1.f / 2048.f) - mu * mu;
    float rs = rsqrtf(var + 1e-5f);
    float* orow = out + (size_t)n * E;
#pragma unroll
    for (int i = 0; i < 8; i++) {
        int c = tid * 8 + i;
        orow[c] = (y[i] - mu) * rs * g[c] + be[c];
    }
}

// ---------------- launch ----------------
extern "C" void kernel_launch(void* const* d_in, const int* in_sizes, int n_in,
                              void* d_out, int out_size, void* d_ws, size_t ws_size,
                              hipStream_t stream) {
    (void)in_sizes; (void)n_in; (void)out_size; (void)ws_size;
    const float* x   = (const float*)d_in[0];
    const float* Wq  = (const float*)d_in[1];
    const float* Wk  = (const float*)d_in[2];
    const float* Wv  = (const float*)d_in[3];
    const float* Wo  = (const float*)d_in[4];
    const float* qnw = (const float*)d_in[5];
    const float* knw = (const float*)d_in[6];
    const float* lng = (const float*)d_in[7];
    const float* lnb = (const float*)d_in[8];
    float* out = (float*)d_out;

    char* ws = (char*)d_ws;
    size_t off = 0;
    auto alloc = [&](size_t bytes) -> char* {
        char* pp = ws + off;
        off = (off + bytes + 255) & ~(size_t)255;
        return pp;
    };
    u16*  xb    = (u16*)alloc((size_t)NTOK * E * 2);     // later reused as attn_out
    u16*  Wqb   = (u16*)alloc((size_t)E * E * 2);
    u16*  Wkvb  = (u16*)alloc((size_t)1024 * E * 2);     // [Wk; Wv]
    u16*  Wob   = (u16*)alloc((size_t)E * E * 2);
    float* qraw = (float*)alloc((size_t)NTOK * E * 4);   // later reused as proj
    float* kvraw= (float*)alloc((size_t)NTOK * 1024 * 4);
    u16*  qaa   = (u16*)alloc((size_t)NTOK * E * 2);
    u16*  kaa   = (u16*)alloc((size_t)NTOK * 512 * 2);
    u16*  vtt   = (u16*)alloc((size_t)NTOK * 512 * 2);
    u16*  attn_o = xb;
    float* proj  = qraw;

    cvtbf<<<dim3((NTOK * E / 4) / 256), 256, 0, stream>>>(x, xb, NTOK * E / 4);
    cvtbf<<<dim3((E * E / 4) / 256), 256, 0, stream>>>(Wq, Wqb, E * E / 4);
    cvtbf<<<dim3((512 * E / 4) / 256), 256, 0, stream>>>(Wk, Wkvb, 512 * E / 4);
    cvtbf<<<dim3((512 * E / 4) / 256), 256, 0, stream>>>(Wv, Wkvb + (size_t)512 * E, 512 * E / 4);
    cvtbf<<<dim3((E * E / 4) / 256), 256, 0, stream>>>(Wo, Wob, E * E / 4);

    gemm_bt<<<dim3(E / TN, NTOK / TM), 256, 0, stream>>>(xb, Wqb, qraw, NTOK, E, E);
    gemm_bt<<<dim3(1024 / TN, NTOK / TM), 256, 0, stream>>>(xb, Wkvb, kvraw, NTOK, 1024, E);

    rmsrope<<<dim3(NTOK * NH / 4), 256, 0, stream>>>(qraw, qnw, qaa, NH, E);
    rmsrope<<<dim3(NTOK * NKVH / 4), 256, 0, stream>>>(kvraw, knw, kaa, NKVH, 1024);
    vtrans<<<dim3(S / 64, NKVH, 2), 256, 0, stream>>>(kvraw, vtt);

    attn_mfma<<<dim3(S / 64, NH, 2), 256, 0, stream>>>(qaa, kaa, vtt, attn_o);

    gemm_bt<<<dim3(E / TN, NTOK / TM), 256, 0, stream>>>(attn_o, Wob, proj, NTOK, E, E);

    ln_kernel<<<dim3(NTOK), 256, 0, stream>>>(x, proj, lng, lnb, out);
}

// Round 4
// 378.184 us; speedup vs baseline: 3.7795x; 1.0446x over previous
//
#include <hip/hip_runtime.h>
#include <stdint.h>

typedef __attribute__((ext_vector_type(8))) short short8;
typedef __attribute__((ext_vector_type(4))) float f32x4;
typedef unsigned short u16;
typedef unsigned int u32;

#define NTOK 4096   // B*S
#define E 2048
#define S 2048
#define NH 16
#define NKVH 4
#define HD 128

__device__ __forceinline__ float bf2f(u16 u) {
    return __uint_as_float(((u32)u) << 16);
}
__device__ __forceinline__ u16 f2bf(float f) {
    u32 u = __float_as_uint(f);
    u32 r = (u + 0x7fffu + ((u >> 16) & 1u)) >> 16;
    return (u16)r;
}
__device__ __forceinline__ void gload_lds16(const u16* g, u16* l) {
    __builtin_amdgcn_global_load_lds(
        (const __attribute__((address_space(1))) unsigned int*)(g),
        (__attribute__((address_space(3))) unsigned int*)(l), 16, 0, 0);
}

// ---------------- fused fp32 -> bf16 cast of all 5 tensors ----------------
// f4-unit boundaries: x 2097152 | Wq 1048576 | Wk 262144 | Wv 262144 | Wo 1048576
__global__ void cast5(const float* __restrict__ x, const float* __restrict__ wq,
                      const float* __restrict__ wk, const float* __restrict__ wv,
                      const float* __restrict__ wo,
                      u16* __restrict__ xb, u16* __restrict__ wqb,
                      u16* __restrict__ wkvb, u16* __restrict__ wob) {
    int i = blockIdx.x * 256 + threadIdx.x;
    const float* s; u16* d; int rel;
    if (i < 2097152)      { s = x;  d = xb;  rel = i; }
    else if (i < 3145728) { s = wq; d = wqb; rel = i - 2097152; }
    else if (i < 3407872) { s = wk; d = wkvb; rel = i - 3145728; }
    else if (i < 3670016) { s = wv; d = wkvb + 1048576; rel = i - 3407872; }
    else                  { s = wo; d = wob; rel = i - 3670016; }
    float4 v = *(const float4*)(s + (size_t)rel * 4);
    ushort4 o;
    o.x = f2bf(v.x); o.y = f2bf(v.y); o.z = f2bf(v.z); o.w = f2bf(v.w);
    *(ushort4*)(d + (size_t)rel * 4) = o;
}

// ---------------- bf16 GEMM, C[M,N] = A[M,K] * Bt[N,K]^T, m97-style async staging ----------
#define TM 128
#define TN 128
#define BK 64

__global__ __launch_bounds__(256, 2)
void gemm_bt(const u16* __restrict__ A, const u16* __restrict__ Bt, float* __restrict__ C,
             int M, int N, int K) {
    __shared__ u16 As[TM * BK];
    __shared__ u16 Bs[TN * BK];
    const int m0 = blockIdx.y * TM;
    const int n0 = blockIdx.x * TN;
    const int tid = threadIdx.x;
    const int w = tid >> 6, lane = tid & 63;
    const int wm = (w >> 1) * 64, wn = (w & 1) * 64;
    const int lr = lane & 15, quad = lane >> 4;

    f32x4 acc[4][4];
#pragma unroll
    for (int mi = 0; mi < 4; mi++)
#pragma unroll
        for (int ni = 0; ni < 4; ni++)
            acc[mi][ni] = (f32x4){0.f, 0.f, 0.f, 0.f};

    const int srow = w * 8 + (lane >> 3);
    const int scol = (lane & 7) * 8;
    const u16* ga0 = A + (size_t)(m0 + srow) * K + scol;
    const u16* gb0 = Bt + (size_t)(n0 + srow) * K + scol;

    for (int kt = 0; kt < K; kt += BK) {
        __syncthreads();
#pragma unroll
        for (int i = 0; i < 4; i++) {
            gload_lds16(ga0 + (size_t)(i * 32) * K + kt, &As[(w * 8 + i * 32) * BK]);
            gload_lds16(gb0 + (size_t)(i * 32) * K + kt, &Bs[(w * 8 + i * 32) * BK]);
        }
        __syncthreads();
#pragma unroll
        for (int kk = 0; kk < BK; kk += 32) {
            const int ko = kk + quad * 8;
            short8 af[4], bfr[4];
#pragma unroll
            for (int mi = 0; mi < 4; mi++)
                af[mi] = *(const short8*)(&As[(wm + mi * 16 + lr) * BK + ko]);
#pragma unroll
            for (int ni = 0; ni < 4; ni++)
                bfr[ni] = *(const short8*)(&Bs[(wn + ni * 16 + lr) * BK + ko]);
#pragma unroll
            for (int mi = 0; mi < 4; mi++)
#pragma unroll
                for (int ni = 0; ni < 4; ni++)
                    acc[mi][ni] = __builtin_amdgcn_mfma_f32_16x16x32_bf16(
                        af[mi], bfr[ni], acc[mi][ni], 0, 0, 0);
        }
    }
#pragma unroll
    for (int mi = 0; mi < 4; mi++)
#pragma unroll
        for (int ni = 0; ni < 4; ni++) {
            int row = m0 + wm + mi * 16 + quad * 4;
            int col = n0 + wn + ni * 16 + lr;
            f32x4 v = acc[mi][ni];
            C[(size_t)(row + 0) * N + col] = v[0];
            C[(size_t)(row + 1) * N + col] = v[1];
            C[(size_t)(row + 2) * N + col] = v[2];
            C[(size_t)(row + 3) * N + col] = v[3];
        }
}

// ---------------- RMSNorm + RoPE for BOTH q and k in one dispatch ----------------
__global__ __launch_bounds__(256)
void rmsrope2(const float* __restrict__ qsrc, const float* __restrict__ ksrc,
              const float* __restrict__ qw, const float* __restrict__ kw,
              u16* __restrict__ qdst, u16* __restrict__ kdst) {
    int p = blockIdx.x * 4 + (threadIdx.x >> 6);
    int lane = threadIdx.x & 63;
    const float* src; const float* w; u16* dst; int HH, rowstride;
    if (p < NTOK * NH) { src = qsrc; w = qw; dst = qdst; HH = NH; rowstride = E; }
    else { p -= NTOK * NH; src = ksrc; w = kw; dst = kdst; HH = NKVH; rowstride = 1024; }
    int n = p / HH;
    int h = p - n * HH;
    int b = n >> 11;
    int s = n & 2047;
    const float* row = src + (size_t)n * rowstride + h * HD;
    float t1 = row[lane];
    float t2 = row[lane + 64];
    float ss = t1 * t1 + t2 * t2;
#pragma unroll
    for (int o = 1; o < 64; o <<= 1) ss += __shfl_xor(ss, o);
    float r = rsqrtf(ss * (1.f / 128.f) + 1e-6f);
    float a1 = t1 * r * w[lane];
    float a2 = t2 * r * w[lane + 64];
    float freq = expf(lane * -0.14391156831212787f);
    float ang = (float)s * freq;
    float sn, cs;
    sincosf(ang, &sn, &cs);
    float o1 = a1 * cs - a2 * sn;
    float o2 = a2 * cs + a1 * sn;
    size_t base = (((size_t)(b * HH + h)) * S + s) * HD;
    dst[base + lane] = f2bf(o1);
    dst[base + 64 + lane] = f2bf(o2);
}

// ---------------- V: cast + transpose (n, 512 + kh*D+d of kv) fp32 -> Vt (b,kh,d,s) bf16 ----
#define LDT 65
__global__ __launch_bounds__(256)
void vtrans(const float* __restrict__ src, u16* __restrict__ dst) {
    __shared__ u16 Ts[128 * LDT];
    const int t = threadIdx.x;
    const int s0 = blockIdx.x * 64;
    const int kh = blockIdx.y;
    const int b = blockIdx.z;
    const float* base = src + ((size_t)(b * S + s0)) * 1024 + 512 + kh * HD;
#pragma unroll
    for (int i = 0; i < 8; i++) {
        int idx = i * 256 + t;
        int r = idx >> 5, c4 = (idx & 31) * 4;
        float4 v = *(const float4*)(base + (size_t)r * 1024 + c4);
        Ts[(c4 + 0) * LDT + r] = f2bf(v.x);
        Ts[(c4 + 1) * LDT + r] = f2bf(v.y);
        Ts[(c4 + 2) * LDT + r] = f2bf(v.z);
        Ts[(c4 + 3) * LDT + r] = f2bf(v.w);
    }
    __syncthreads();
    u16* obase = dst + ((size_t)(b * NKVH + kh) * HD) * S + s0;
#pragma unroll
    for (int i = 0; i < 4; i++) {
        int idx = i * 256 + t;
        int d = idx >> 3, s8 = (idx & 7) * 8;
        const u16* row = &Ts[d * LDT + s8];
        short8 o;
#pragma unroll
        for (int j = 0; j < 8; j++) o[j] = (short)row[j];
        *(short8*)(obase + (size_t)d * S + s8) = o;
    }
}

// ---------------- MFMA flash attention, fixed-max softmax, XOR-swizzled LDS ----------------
// block: 64 queries x 1 head, 4 waves x 16 queries; KV tiles of 64 keys
// LDS: Ks 16KB + Vs 16KB + Ps 8KB = 40960 B -> 4 blocks/CU
#define KSX(key, cb) ((key) * 128 + ((((cb) ^ ((key) & 15))) * 8))
#define VSX(d, cb)   ((d) * 64 + ((((cb) ^ ((d) & 7))) * 8))
#define PSX(row, cb) ((row) * 64 + ((((cb) ^ ((row) & 7))) * 8))

__global__ __launch_bounds__(256, 4)
void attn_mfma(const u16* __restrict__ qa, const u16* __restrict__ ka,
               const u16* __restrict__ vt, u16* __restrict__ out) {
    __shared__ u16 Ks[64 * 128];
    __shared__ u16 Vs[128 * 64];
    __shared__ u16 Ps[64 * 64];
    const int tid = threadIdx.x;
    const int w = tid >> 6, lane = tid & 63;
    const int lr = lane & 15, quad = lane >> 4;
    const int qt = (int)(gridDim.x - 1) - blockIdx.x;   // heavy blocks first
    const int h = blockIdx.y, b = blockIdx.z;
    const int kh = h >> 2;
    const int q0 = qt * 64;
    const int qw0 = q0 + w * 16;

    const float SCINV = 0.0017677669529663689f;  // 1/(sqrt(128)*50)

    const u16* qrow = qa + (((size_t)(b * NH + h)) * S + qw0 + lr) * HD;
    short8 qf[4];
#pragma unroll
    for (int c = 0; c < 4; c++)
        qf[c] = *(const short8*)(qrow + c * 32 + quad * 8);

    f32x4 O[8];
#pragma unroll
    for (int dt = 0; dt < 8; dt++) O[dt] = (f32x4){0.f, 0.f, 0.f, 0.f};
    float l[4] = {0.f, 0.f, 0.f, 0.f};

    const u16* kbase0 = ka + (((size_t)(b * NKVH + kh)) * S) * HD;
    const u16* vtbase0 = vt + ((size_t)(b * NKVH + kh) * HD) * S;

    const int jt0 = (q0 >= 1024) ? (q0 - 1024) : 0;
    for (int jt = jt0; jt <= q0; jt += 64) {
        __syncthreads();
        const u16* kbase = kbase0 + (size_t)jt * HD;
        const u16* vtbase = vtbase0 + jt;
#pragma unroll
        for (int i = 0; i < 4; i++) {
            int idx = i * 256 + tid;
            int key = idx >> 4, cb = idx & 15;
            *(int4*)(&Ks[KSX(key, cb)]) = *(const int4*)(kbase + (size_t)key * HD + cb * 8);
            int dd = idx >> 3, cb2 = idx & 7;
            *(int4*)(&Vs[VSX(dd, cb2)]) = *(const int4*)(vtbase + (size_t)dd * S + cb2 * 8);
        }
        __syncthreads();

        const bool isDiag = (jt == q0);
        const bool isFirst = (q0 >= 1024) && (jt == jt0);
        u16* Pw = &Ps[w * 16 * 64];

#pragma unroll
        for (int kt = 0; kt < 4; kt++) {
            if ((isDiag && kt > w) || (isFirst && kt < w)) {
#pragma unroll
                for (int r = 0; r < 4; r++)
                    Pw[PSX(quad * 4 + r, kt * 2 + (lr >> 3)) + (lr & 7)] = 0;
                continue;
            }
            f32x4 a = (f32x4){0.f, 0.f, 0.f, 0.f};
#pragma unroll
            for (int c = 0; c < 4; c++) {
                short8 kf = *(const short8*)(&Ks[KSX(kt * 16 + lr, 4 * c + quad)]);
                a = __builtin_amdgcn_mfma_f32_16x16x32_bf16(qf[c], kf, a, 0, 0, 0);
            }
            const bool edge = (isDiag || isFirst) && (kt == w);
#pragma unroll
            for (int r = 0; r < 4; r++) {
                // p = exp(sc - 50), sc = 50*tanh(x) => p = exp(-100/(e^{2x}+1))
                float x = a[r] * SCINV;
                float t = __expf(2.f * x);
                float p = __expf(-100.f * __builtin_amdgcn_rcpf(t + 1.f));
                if (edge) {
                    int rel = kt * 16 + lr - (16 * w + quad * 4 + r);
                    bool valid = isDiag ? (rel <= 0) : (rel > 0);
                    p = valid ? p : 0.f;
                }
                l[r] += p;
                // truncating bf16 pack (P in [0,1], rel err < 2^-8 — fine at our margin)
                Pw[PSX(quad * 4 + r, kt * 2 + (lr >> 3)) + (lr & 7)] =
                    (u16)(__float_as_uint(p) >> 16);
            }
        }

        // PV: O[q][d] += P[q][key] * Vt[d][key]
#pragma unroll
        for (int c2 = 0; c2 < 2; c2++) {
            if ((isDiag && 2 * c2 > w) || (isFirst && 2 * c2 + 1 < w)) continue;
            short8 pf = *(const short8*)(&Pw[PSX(lr, c2 * 4 + quad)]);
#pragma unroll
            for (int dt = 0; dt < 8; dt++) {
                short8 vf = *(const short8*)(&Vs[VSX(dt * 16 + lr, c2 * 4 + quad)]);
                O[dt] = __builtin_amdgcn_mfma_f32_16x16x32_bf16(pf, vf, O[dt], 0, 0, 0);
            }
        }
    }

#pragma unroll
    for (int r = 0; r < 4; r++) {
        l[r] += __shfl_xor(l[r], 1);
        l[r] += __shfl_xor(l[r], 2);
        l[r] += __shfl_xor(l[r], 4);
        l[r] += __shfl_xor(l[r], 8);
    }
#pragma unroll
    for (int r = 0; r < 4; r++) {
        float inv = 1.f / l[r];
        u16* orow = out + ((size_t)(b * S + qw0 + quad * 4 + r)) * E + h * HD;
#pragma unroll
        for (int dt = 0; dt < 8; dt++)
            orow[dt * 16 + lr] = f2bf(O[dt][r] * inv);
    }
}

// ---------------- residual + LayerNorm ----------------
__global__ __launch_bounds__(256)
void ln_kernel(const float* __restrict__ x, const float* __restrict__ pr,
               const float* __restrict__ g, const float* __restrict__ be,
               float* __restrict__ out) {
    int n = blockIdx.x;
    int tid = threadIdx.x;
    const float* xr = x + (size_t)n * E;
    const float* p = pr + (size_t)n * E;
    float y[8];
    float s = 0.f, ss = 0.f;
#pragma unroll
    for (int i = 0; i < 2; i++) {
        float4 a = *(const float4*)(xr + tid * 8 + i * 4);
        float4 b = *(const float4*)(p + tid * 8 + i * 4);
        float v0 = a.x + b.x, v1 = a.y + b.y, v2 = a.z + b.z, v3 = a.w + b.w;
        y[i * 4 + 0] = v0; y[i * 4 + 1] = v1; y[i * 4 + 2] = v2; y[i * 4 + 3] = v3;
        s += v0 + v1 + v2 + v3;
        ss += v0 * v0 + v1 * v1 + v2 * v2 + v3 * v3;
    }
#pragma unroll
    for (int o = 1; o < 64; o <<= 1) {
        s += __shfl_xor(s, o);
        ss += __shfl_xor(ss, o);
    }
    __shared__ float r0[4], r1[4];
    int w = tid >> 6;
    if ((tid & 63) == 0) { r0[w] = s; r1[w] = ss; }
    __syncthreads();
    s = r0[0] + r0[1] + r0[2] + r0[3];
    ss = r1[0] + r1[1] + r1[2] + r1[3];
    float mu = s * (1.f / 2048.f);
    float var = ss * (1.f / 2048.f) - mu * mu;
    float rs = rsqrtf(var + 1e-5f);
    float* orow = out + (size_t)n * E;
#pragma unroll
    for (int i = 0; i < 8; i++) {
        int c = tid * 8 + i;
        orow[c] = (y[i] - mu) * rs * g[c] + be[c];
    }
}

// ---------------- launch ----------------
extern "C" void kernel_launch(void* const* d_in, const int* in_sizes, int n_in,
                              void* d_out, int out_size, void* d_ws, size_t ws_size,
                              hipStream_t stream) {
    (void)in_sizes; (void)n_in; (void)out_size; (void)ws_size;
    const float* x   = (const float*)d_in[0];
    const float* Wq  = (const float*)d_in[1];
    const float* Wk  = (const float*)d_in[2];
    const float* Wv  = (const float*)d_in[3];
    const float* Wo  = (const float*)d_in[4];
    const float* qnw = (const float*)d_in[5];
    const float* knw = (const float*)d_in[6];
    const float* lng = (const float*)d_in[7];
    const float* lnb = (const float*)d_in[8];
    float* out = (float*)d_out;

    char* ws = (char*)d_ws;
    size_t off = 0;
    auto alloc = [&](size_t bytes) -> char* {
        char* pp = ws + off;
        off = (off + bytes + 255) & ~(size_t)255;
        return pp;
    };
    u16*  xb    = (u16*)alloc((size_t)NTOK * E * 2);     // later reused as attn_out
    u16*  Wqb   = (u16*)alloc((size_t)E * E * 2);
    u16*  Wkvb  = (u16*)alloc((size_t)1024 * E * 2);     // [Wk; Wv]
    u16*  Wob   = (u16*)alloc((size_t)E * E * 2);
    float* qraw = (float*)alloc((size_t)NTOK * E * 4);   // later reused as proj
    float* kvraw= (float*)alloc((size_t)NTOK * 1024 * 4);
    u16*  qaa   = (u16*)alloc((size_t)NTOK * E * 2);
    u16*  kaa   = (u16*)alloc((size_t)NTOK * 512 * 2);
    u16*  vtt   = (u16*)alloc((size_t)NTOK * 512 * 2);
    u16*  attn_o = xb;
    float* proj  = qraw;

    cast5<<<dim3(18432), 256, 0, stream>>>(x, Wq, Wk, Wv, Wo, xb, Wqb, Wkvb, Wob);

    gemm_bt<<<dim3(E / TN, NTOK / TM), 256, 0, stream>>>(xb, Wqb, qraw, NTOK, E, E);
    gemm_bt<<<dim3(1024 / TN, NTOK / TM), 256, 0, stream>>>(xb, Wkvb, kvraw, NTOK, 1024, E);

    rmsrope2<<<dim3((NTOK * NH + NTOK * NKVH) / 4), 256, 0, stream>>>(
        qraw, kvraw, qnw, knw, qaa, kaa);
    vtrans<<<dim3(S / 64, NKVH, 2), 256, 0, stream>>>(kvraw, vtt);

    attn_mfma<<<dim3(S / 64, NH, 2), 256, 0, stream>>>(qaa, kaa, vtt, attn_o);

    gemm_bt<<<dim3(E / TN, NTOK / TM), 256, 0, stream>>>(attn_o, Wob, proj, NTOK, E, E);

    ln_kernel<<<dim3(NTOK), 256, 0, stream>>>(x, proj, lng, lnb, out);
}